// Round 1
// baseline (569.092 us; speedup 1.0000x reference)
//
#include <hip/hip_runtime.h>

#define MM 1024
#define NN 4096
#define DD 128
#define HH 32
#define LL 4096
#define PP 2048

typedef __attribute__((ext_vector_type(8))) short short8;
typedef __attribute__((ext_vector_type(4))) float f32x4;

__device__ __forceinline__ ushort f2bf(float f) {
  unsigned u = __builtin_bit_cast(unsigned, f);
  u += 0x7fffu + ((u >> 16) & 1u);
  return (ushort)(u >> 16);
}

__device__ __forceinline__ void gl_lds16(const void* g, void* l) {
  __builtin_amdgcn_global_load_lds(
      (const __attribute__((address_space(1))) void*)g,
      (__attribute__((address_space(3))) void*)l, 16, 0, 0);
}

// ---------------- fp32 -> bf16 convert (8 elts/thread) ----------------
__global__ __launch_bounds__(256) void convert_kernel(
    const float* __restrict__ src, ushort* __restrict__ dst, int n8) {
  int i = blockIdx.x * 256 + threadIdx.x;
  if (i >= n8) return;
  const float4* s = (const float4*)src + (size_t)i * 2;
  float4 a = s[0], b = s[1];
  union { ushort s[8]; uint4 v; } pk;
  pk.s[0] = f2bf(a.x); pk.s[1] = f2bf(a.y);
  pk.s[2] = f2bf(a.z); pk.s[3] = f2bf(a.w);
  pk.s[4] = f2bf(b.x); pk.s[5] = f2bf(b.y);
  pk.s[6] = f2bf(b.z); pk.s[7] = f2bf(b.w);
  ((uint4*)dst)[i] = pk.v;
}

// ------- transpose+convert W (3x fp32 [N,N] -> bf16 Wt[j][k] = W[k][j]) -------
__global__ __launch_bounds__(256) void transpose_w_kernel(
    const float* __restrict__ W0, const float* __restrict__ W1,
    const float* __restrict__ W2, ushort* __restrict__ Wt) {
  __shared__ __align__(16) ushort tile[64][72];  // 144B pitch (16B-aligned)
  int z = blockIdx.z;
  const float* W = (z == 0) ? W0 : ((z == 1) ? W1 : W2);
  ushort* out = Wt + (size_t)z * NN * NN;
  int r0 = blockIdx.x * 64, c0 = blockIdx.y * 64;
  int t = threadIdx.x;
#pragma unroll
  for (int i = 0; i < 4; ++i) {
    int c = i * 256 + t;
    int r = c >> 4, cc = (c & 15) * 4;
    float4 v = *(const float4*)(W + (size_t)(r0 + r) * NN + c0 + cc);
    tile[r][cc + 0] = f2bf(v.x);
    tile[r][cc + 1] = f2bf(v.y);
    tile[r][cc + 2] = f2bf(v.z);
    tile[r][cc + 3] = f2bf(v.w);
  }
  __syncthreads();
#pragma unroll
  for (int i = 0; i < 2; ++i) {
    int c = i * 256 + t;
    int j = c >> 3, kk = (c & 7) * 8;
    union { ushort s[8]; uint4 v; } pk;
#pragma unroll
    for (int u = 0; u < 8; ++u) pk.s[u] = tile[kk + u][j];
    *(uint4*)(out + (size_t)(c0 + j) * NN + r0 + kk) = pk.v;
  }
}

// --- build bf16 Vt[h][d][l] from fp32 cache_V (+ bf16 new v rows at P..P+M) ---
__global__ __launch_bounds__(256) void transpose_v_kernel(
    const float* __restrict__ cacheV, const ushort* __restrict__ v_new,
    ushort* __restrict__ Vt) {
  __shared__ __align__(16) ushort tile[64][72];
  int l0 = blockIdx.x * 64, d0 = blockIdx.y * 64, h = blockIdx.z;
  int t = threadIdx.x;
  bool isnew = (l0 >= PP && l0 < PP + MM);
  if (isnew) {
    const ushort* src = v_new + (size_t)(l0 - PP) * NN + h * DD + d0;
#pragma unroll
    for (int i = 0; i < 2; ++i) {
      int c = i * 256 + t;
      int r = c >> 3, cc = (c & 7) * 8;
      *(uint4*)&tile[r][cc] = *(const uint4*)(src + (size_t)r * NN + cc);
    }
  } else {
    const float* src = cacheV + ((size_t)h * LL + l0) * DD + d0;
#pragma unroll
    for (int i = 0; i < 4; ++i) {
      int c = i * 256 + t;
      int r = c >> 4, cc = (c & 15) * 4;
      float4 v = *(const float4*)(src + (size_t)r * DD + cc);
      tile[r][cc + 0] = f2bf(v.x);
      tile[r][cc + 1] = f2bf(v.y);
      tile[r][cc + 2] = f2bf(v.z);
      tile[r][cc + 3] = f2bf(v.w);
    }
  }
  __syncthreads();
#pragma unroll
  for (int i = 0; i < 2; ++i) {
    int c = i * 256 + t;
    int j = c >> 3, kk = (c & 7) * 8;
    union { ushort s[8]; uint4 v; } pk;
#pragma unroll
    for (int u = 0; u < 8; ++u) pk.s[u] = tile[kk + u][j];
    *(uint4*)(Vt + ((size_t)(h * DD + d0 + j)) * LL + l0 + kk) = pk.v;
  }
}

// ---------------- QKV GEMM: C[m][col] = sum_k Xb[m][k] * Wt[col][k] ----------------
// 128x128 tile, BK=64, global_load_lds(16B), XOR-swizzled LDS chunks.
__global__ __launch_bounds__(256) void qkv_gemm_kernel(
    const ushort* __restrict__ X, const ushort* __restrict__ Wt,
    ushort* __restrict__ q_ws, ushort* __restrict__ k_ws,
    ushort* __restrict__ v_ws) {
  __shared__ __align__(16) ushort Alds[128 * 64];
  __shared__ __align__(16) ushort Blds[128 * 64];
  int t = threadIdx.x;
  int lane = t & 63, quad = lane >> 4, l15 = lane & 15;
  int wv = t >> 6, wm = wv >> 1, wn = wv & 1;
  int m0 = blockIdx.x * 128;
  int wsel = blockIdx.y >> 5;
  int col0 = (blockIdx.y & 31) * 128;
  const ushort* Wsrc = Wt + (size_t)wsel * NN * NN + (size_t)col0 * NN;
  ushort* dst = (wsel == 0) ? q_ws : ((wsel == 1) ? k_ws : v_ws);

  int wuni = __builtin_amdgcn_readfirstlane(t & 192);  // wave base thread

  const ushort* aG[4];
  const ushort* bG[4];
  unsigned ldsb[4];
#pragma unroll
  for (int i = 0; i < 4; ++i) {
    int c = i * 256 + t;
    int row = c >> 3, g = (c & 7) ^ (row & 7);
    aG[i] = X + (size_t)(m0 + row) * NN + g * 8;
    bG[i] = Wsrc + (size_t)row * NN + g * 8;
    ldsb[i] = (unsigned)(i * 256 + wuni) * 16u;
  }
  unsigned aAddr[4][2], bAddr[4][2];
#pragma unroll
  for (int mb = 0; mb < 4; ++mb)
#pragma unroll
    for (int s = 0; s < 2; ++s) {
      int row = wm * 64 + mb * 16 + l15;
      int g = s * 4 + quad;
      aAddr[mb][s] = (unsigned)(row * 128 + ((g ^ (row & 7)) * 16));
    }
#pragma unroll
  for (int nb = 0; nb < 4; ++nb)
#pragma unroll
    for (int s = 0; s < 2; ++s) {
      int row = wn * 64 + nb * 16 + l15;
      int g = s * 4 + quad;
      bAddr[nb][s] = (unsigned)(row * 128 + ((g ^ (row & 7)) * 16));
    }

  f32x4 acc[4][4];
#pragma unroll
  for (int mb = 0; mb < 4; ++mb)
#pragma unroll
    for (int nb = 0; nb < 4; ++nb) acc[mb][nb] = (f32x4){0.f, 0.f, 0.f, 0.f};

  for (int kt = 0; kt < 64; ++kt) {
#pragma unroll
    for (int i = 0; i < 4; ++i) gl_lds16(aG[i], (char*)Alds + ldsb[i]);
#pragma unroll
    for (int i = 0; i < 4; ++i) gl_lds16(bG[i], (char*)Blds + ldsb[i]);
#pragma unroll
    for (int i = 0; i < 4; ++i) { aG[i] += 64; bG[i] += 64; }
    __syncthreads();  // drains vmcnt -> tiles visible
#pragma unroll
    for (int s = 0; s < 2; ++s) {
      short8 af[4], bf[4];
#pragma unroll
      for (int mb = 0; mb < 4; ++mb)
        af[mb] = *(const short8*)((const char*)Alds + aAddr[mb][s]);
#pragma unroll
      for (int nb = 0; nb < 4; ++nb)
        bf[nb] = *(const short8*)((const char*)Blds + bAddr[nb][s]);
#pragma unroll
      for (int mb = 0; mb < 4; ++mb)
#pragma unroll
        for (int nb = 0; nb < 4; ++nb)
          acc[mb][nb] = __builtin_amdgcn_mfma_f32_16x16x32_bf16(
              af[mb], bf[nb], acc[mb][nb], 0, 0, 0);
    }
    __syncthreads();  // done reading before next stage overwrites
  }

#pragma unroll
  for (int mb = 0; mb < 4; ++mb)
#pragma unroll
    for (int nb = 0; nb < 4; ++nb)
#pragma unroll
      for (int r = 0; r < 4; ++r) {
        int row = m0 + wm * 64 + mb * 16 + quad * 4 + r;
        int col = col0 + wn * 64 + nb * 16 + l15;
        dst[(size_t)row * NN + col] = f2bf(acc[mb][nb][r]);
      }
}

// ---------------- fused attention: one head x 64 queries per block ----------------
// Pipelined: K double-buffered in LDS with 1-tile-ahead global_load_lds prefetch
// and counted vmcnt (never 0 in steady state); V staged at top of iteration and
// waited only at vmcnt(4) after QK^T (latency hidden under MFMA+exp).
__global__ __launch_bounds__(256) void attn_kernel(
    const ushort* __restrict__ q_ws, const ushort* __restrict__ k_ws,
    const ushort* __restrict__ Kb, const ushort* __restrict__ Vt,
    float* __restrict__ out) {
  // LDS layout:
  //   Klds[2]: [64l][128d] bf16, xor16 chunk swizzle @0 / @16384  (32 KiB)
  //   Vlds:    [128d][64l] bf16, xor8                @32768       (16 KiB)
  //   Plds:    [64m][72l]  bf16, pitch 144B          @49152       (9216 B)
  //   den:     float[64]                             @58368       (256 B)
  //   Olds:    float[64][136] (epilogue reuse)       @0           (34816 B)
  // 58.6 KB -> 2 blocks/CU; grid 512 = 2/CU fully co-resident.
  __shared__ __align__(16) char smem[58624];
  float* denlds = (float*)(smem + 58368);
  float* Olds = (float*)smem;

  int t = threadIdx.x;
  int lane = t & 63, quad = lane >> 4, l15 = lane & 15;
  int wv = t >> 6;
  // XCD-aware bijective swizzle (512 blocks % 8 XCDs == 0):
  // each XCD gets a contiguous chunk of 64 blocks = 4 heads -> K/V L2-resident.
  int flat = (int)(blockIdx.y * 16 + blockIdx.x);
  int swz = ((flat & 7) << 6) | (flat >> 3);
  int m0 = (swz & 15) * 64;
  int h = swz >> 4;
  int wuni = __builtin_amdgcn_readfirstlane(t & 192);

  // Q fragments (A-layout): rows m0 + wv*16 + l15
  short8 qf[4];
  {
    const ushort* qrow =
        q_ws + (size_t)(m0 + wv * 16 + l15) * NN + h * DD + quad * 8;
#pragma unroll
    for (int s = 0; s < 4; ++s) qf[s] = *(const short8*)(qrow + s * 32);
  }

  // staging maps
  int kRow[4], kOff[4];
  unsigned kLb[4];
  const ushort* vG[4];
  unsigned vLb[4];
#pragma unroll
  for (int i = 0; i < 4; ++i) {
    int c = i * 256 + t;
    int krow = c >> 4, kg = (c & 15) ^ (krow & 15);
    kRow[i] = krow; kOff[i] = kg * 8;
    kLb[i] = (unsigned)(i * 256 + wuni) * 16u;
    int vrow = c >> 3, vg = (c & 7) ^ (vrow & 7);
    vG[i] = Vt + ((size_t)(h * DD + vrow)) * LL + vg * 8;
    vLb[i] = 32768u + (unsigned)(i * 256 + wuni) * 16u;
  }
  // fragment LDS addresses (iteration-invariant)
  unsigned kAddr[4][4], vAddr[2][2], pAddr[2][4];
#pragma unroll
  for (int lb = 0; lb < 4; ++lb)
#pragma unroll
    for (int ds = 0; ds < 4; ++ds) {
      int l = lb * 16 + l15, g = ds * 4 + quad;
      kAddr[lb][ds] = (unsigned)(l * 256 + ((g ^ l15) * 16));
    }
#pragma unroll
  for (int ls = 0; ls < 2; ++ls)
#pragma unroll
    for (int db = 0; db < 2; ++db) {
      int d = wv * 32 + db * 16 + l15, g = ls * 4 + quad;
      vAddr[ls][db] = 32768u + (unsigned)(d * 128 + ((g ^ (l15 & 7)) * 16));
    }
#pragma unroll
  for (int ls = 0; ls < 2; ++ls)
#pragma unroll
    for (int mb = 0; mb < 4; ++mb)
      pAddr[ls][mb] =
          49152u + (unsigned)((mb * 16 + l15) * 144 + ls * 64 + quad * 16);

  f32x4 Oacc[2][4];
#pragma unroll
  for (int db = 0; db < 2; ++db)
#pragma unroll
    for (int mb = 0; mb < 4; ++mb) Oacc[db][mb] = (f32x4){0.f, 0.f, 0.f, 0.f};
  float denp[4] = {0.f, 0.f, 0.f, 0.f};

  // prologue: stage K tile 0 into Klds buf 0 (l0 = 0 -> cache region)
  {
    const ushort* ks = Kb + (size_t)h * LL * DD;
#pragma unroll
    for (int i = 0; i < 4; ++i)
      gl_lds16(ks + (size_t)kRow[i] * DD + kOff[i], smem + kLb[i]);
  }

  for (int lt = 0; lt < 64; ++lt) {
    unsigned krd = (unsigned)(lt & 1) << 14;  // read buffer base
    // (1) issue K prefetch for tile lt+1 into the other buffer
    if (lt < 63) {
      int l0n = (lt + 1) * 64;
      const ushort* ks2;
      size_t kst2;
      if (l0n >= PP && l0n < PP + MM) {
        ks2 = k_ws + (size_t)(l0n - PP) * NN + h * DD;
        kst2 = NN;
      } else {
        ks2 = Kb + ((size_t)h * LL + l0n) * DD;
        kst2 = DD;
      }
      unsigned kb = krd ^ 16384u;
#pragma unroll
      for (int i = 0; i < 4; ++i)
        gl_lds16(ks2 + (size_t)kRow[i] * kst2 + kOff[i], smem + kb + kLb[i]);
    }
    // (2) issue V stage for tile lt (single buffer, consumed after barrier 2)
#pragma unroll
    for (int i = 0; i < 4; ++i) {
      gl_lds16(vG[i], smem + vLb[i]);
      vG[i] += 64;
    }
    // (3) wait K(lt) ready; leave K(lt+1)+V(lt) = 8 loads in flight
    if (lt < 63)
      asm volatile("s_waitcnt vmcnt(8)" ::: "memory");
    else
      asm volatile("s_waitcnt vmcnt(4)" ::: "memory");
    __builtin_amdgcn_s_barrier();
    asm volatile("" ::: "memory");

    // (4) S = Q K^T, exp, write P to LDS, accumulate denominator
    __builtin_amdgcn_s_setprio(1);
#pragma unroll
    for (int lb = 0; lb < 4; ++lb) {
      f32x4 s = (f32x4){0.f, 0.f, 0.f, 0.f};
#pragma unroll
      for (int ds = 0; ds < 4; ++ds) {
        short8 bk = *(const short8*)(smem + krd + kAddr[lb][ds]);
        s = __builtin_amdgcn_mfma_f32_16x16x32_bf16(qf[ds], bk, s, 0, 0, 0);
      }
#pragma unroll
      for (int r = 0; r < 4; ++r) {
        float e = __expf(s[r]);
        denp[r] += e;
        *(ushort*)(smem + 49152 + (wv * 16 + quad * 4 + r) * 144 +
                   (lb * 16 + l15) * 2) = f2bf(e);
      }
    }
    __builtin_amdgcn_s_setprio(0);

    // (5) V(lt) landed + P written; leave only K(lt+1) in flight
    if (lt < 63)
      asm volatile("s_waitcnt vmcnt(4) lgkmcnt(0)" ::: "memory");
    else
      asm volatile("s_waitcnt vmcnt(0) lgkmcnt(0)" ::: "memory");
    __builtin_amdgcn_s_barrier();
    asm volatile("" ::: "memory");

    // (6) O^T += V^T P^T  (wave wv owns d rows [wv*32, wv*32+32))
    __builtin_amdgcn_s_setprio(1);
#pragma unroll
    for (int ls = 0; ls < 2; ++ls) {
      short8 av0 = *(const short8*)(smem + vAddr[ls][0]);
      short8 av1 = *(const short8*)(smem + vAddr[ls][1]);
#pragma unroll
      for (int mb = 0; mb < 4; ++mb) {
        short8 bp = *(const short8*)(smem + pAddr[ls][mb]);
        Oacc[0][mb] =
            __builtin_amdgcn_mfma_f32_16x16x32_bf16(av0, bp, Oacc[0][mb], 0, 0, 0);
        Oacc[1][mb] =
            __builtin_amdgcn_mfma_f32_16x16x32_bf16(av1, bp, Oacc[1][mb], 0, 0, 0);
      }
    }
    __builtin_amdgcn_s_setprio(0);

    // (7) all reads of Vlds/Plds done before next iteration's writes
    asm volatile("" ::: "memory");
    __builtin_amdgcn_s_barrier();
    asm volatile("" ::: "memory");
  }

  __syncthreads();  // final PV done; smem reusable
  // denominator reduction across the 16 cols (lane bits 0..3)
#pragma unroll
  for (int r = 0; r < 4; ++r) {
    float v = denp[r];
    v += __shfl_xor(v, 1);
    v += __shfl_xor(v, 2);
    v += __shfl_xor(v, 4);
    v += __shfl_xor(v, 8);
    denp[r] = v;
  }
  if (l15 == 0) {
#pragma unroll
    for (int r = 0; r < 4; ++r) denlds[wv * 16 + quad * 4 + r] = denp[r];
  }
  __syncthreads();

  // divide + transpose O^T -> O via LDS (fp32, pitch 136)
#pragma unroll
  for (int mb = 0; mb < 4; ++mb) {
    float inv = 1.0f / denlds[mb * 16 + l15];
#pragma unroll
    for (int db = 0; db < 2; ++db)
#pragma unroll
      for (int r = 0; r < 4; ++r) {
        int d = wv * 32 + db * 16 + quad * 4 + r;
        Olds[(mb * 16 + l15) * 136 + d] = Oacc[db][mb][r] * inv;
      }
  }
  __syncthreads();
  {
    int m = t >> 2, c0 = (t & 3) * 32;
    float* orow = out + (size_t)(m0 + m) * NN + h * DD + c0;
#pragma unroll
    for (int j = 0; j < 32; j += 4) {
      float4 v;
      v.x = Olds[m * 136 + c0 + j + 0];
      v.y = Olds[m * 136 + c0 + j + 1];
      v.z = Olds[m * 136 + c0 + j + 2];
      v.w = Olds[m * 136 + c0 + j + 3];
      *(float4*)(orow + j) = v;
    }
  }
}

extern "C" void kernel_launch(void* const* d_in, const int* in_sizes, int n_in,
                              void* d_out, int out_size, void* d_ws,
                              size_t ws_size, hipStream_t stream) {
  const float* X = (const float*)d_in[0];
  const float* Wq = (const float*)d_in[1];
  const float* Wk = (const float*)d_in[2];
  const float* Wv = (const float*)d_in[3];
  const float* cK = (const float*)d_in[4];
  const float* cV = (const float*)d_in[5];
  float* out = (float*)d_out;
  char* wsb = (char*)d_ws;

  // ws layout (bytes) — Kb/Vt alias Wt (dead after GEMM). Total 128 MiB.
  ushort* Wt = (ushort*)wsb;                         // 100,663,296
  ushort* Kb = (ushort*)wsb;                         // 33,554,432 (alias)
  ushort* Vt = (ushort*)(wsb + 33554432);            // 33,554,432 (alias)
  ushort* Xb = (ushort*)(wsb + 100663296);           // 8,388,608
  ushort* q_ws = (ushort*)(wsb + 109051904);         // 8,388,608
  ushort* k_ws = (ushort*)(wsb + 117440512);         // 8,388,608
  ushort* v_ws = (ushort*)(wsb + 125829120);         // 8,388,608

  convert_kernel<<<2048, 256, 0, stream>>>(X, Xb, MM * NN / 8);
  transpose_w_kernel<<<dim3(64, 64, 3), 256, 0, stream>>>(Wq, Wk, Wv, Wt);
  qkv_gemm_kernel<<<dim3(8, 96), 256, 0, stream>>>(Xb, Wt, q_ws, k_ws, v_ws);
  convert_kernel<<<8192, 256, 0, stream>>>(cK, Kb, HH * LL * DD / 8);
  transpose_v_kernel<<<dim3(64, 2, 32), 256, 0, stream>>>(cV, v_ws, Vt);
  attn_kernel<<<dim3(16, 32), 256, 0, stream>>>(q_ws, k_ws, Kb, Vt, out);
}

// Round 2
// 560.073 us; speedup vs baseline: 1.0161x; 1.0161x over previous
//
#include <hip/hip_runtime.h>

#define MM 1024
#define NN 4096
#define DD 128
#define HH 32
#define LL 4096
#define PP 2048

typedef __attribute__((ext_vector_type(8))) short short8;
typedef __attribute__((ext_vector_type(4))) float f32x4;

__device__ __forceinline__ ushort f2bf(float f) {
  unsigned u = __builtin_bit_cast(unsigned, f);
  u += 0x7fffu + ((u >> 16) & 1u);
  return (ushort)(u >> 16);
}

__device__ __forceinline__ void gl_lds16(const void* g, void* l) {
  __builtin_amdgcn_global_load_lds(
      (const __attribute__((address_space(1))) void*)g,
      (__attribute__((address_space(3))) void*)l, 16, 0, 0);
}

// ---------------- fp32 -> bf16 convert (8 elts/thread) ----------------
__global__ __launch_bounds__(256) void convert_kernel(
    const float* __restrict__ src, ushort* __restrict__ dst, int n8) {
  int i = blockIdx.x * 256 + threadIdx.x;
  if (i >= n8) return;
  const float4* s = (const float4*)src + (size_t)i * 2;
  float4 a = s[0], b = s[1];
  union { ushort s[8]; uint4 v; } pk;
  pk.s[0] = f2bf(a.x); pk.s[1] = f2bf(a.y);
  pk.s[2] = f2bf(a.z); pk.s[3] = f2bf(a.w);
  pk.s[4] = f2bf(b.x); pk.s[5] = f2bf(b.y);
  pk.s[6] = f2bf(b.z); pk.s[7] = f2bf(b.w);
  ((uint4*)dst)[i] = pk.v;
}

// ------- transpose+convert W (3x fp32 [N,N] -> bf16 Wt[j][k] = W[k][j]) -------
__global__ __launch_bounds__(256) void transpose_w_kernel(
    const float* __restrict__ W0, const float* __restrict__ W1,
    const float* __restrict__ W2, ushort* __restrict__ Wt) {
  __shared__ __align__(16) ushort tile[64][72];  // 144B pitch (16B-aligned)
  int z = blockIdx.z;
  const float* W = (z == 0) ? W0 : ((z == 1) ? W1 : W2);
  ushort* out = Wt + (size_t)z * NN * NN;
  int r0 = blockIdx.x * 64, c0 = blockIdx.y * 64;
  int t = threadIdx.x;
#pragma unroll
  for (int i = 0; i < 4; ++i) {
    int c = i * 256 + t;
    int r = c >> 4, cc = (c & 15) * 4;
    float4 v = *(const float4*)(W + (size_t)(r0 + r) * NN + c0 + cc);
    tile[r][cc + 0] = f2bf(v.x);
    tile[r][cc + 1] = f2bf(v.y);
    tile[r][cc + 2] = f2bf(v.z);
    tile[r][cc + 3] = f2bf(v.w);
  }
  __syncthreads();
#pragma unroll
  for (int i = 0; i < 2; ++i) {
    int c = i * 256 + t;
    int j = c >> 3, kk = (c & 7) * 8;
    union { ushort s[8]; uint4 v; } pk;
#pragma unroll
    for (int u = 0; u < 8; ++u) pk.s[u] = tile[kk + u][j];
    *(uint4*)(out + (size_t)(c0 + j) * NN + r0 + kk) = pk.v;
  }
}

// --- build bf16 Vt[h][d][l] from fp32 cache_V (+ bf16 new v rows at P..P+M) ---
__global__ __launch_bounds__(256) void transpose_v_kernel(
    const float* __restrict__ cacheV, const ushort* __restrict__ v_new,
    ushort* __restrict__ Vt) {
  __shared__ __align__(16) ushort tile[64][72];
  int l0 = blockIdx.x * 64, d0 = blockIdx.y * 64, h = blockIdx.z;
  int t = threadIdx.x;
  bool isnew = (l0 >= PP && l0 < PP + MM);
  if (isnew) {
    const ushort* src = v_new + (size_t)(l0 - PP) * NN + h * DD + d0;
#pragma unroll
    for (int i = 0; i < 2; ++i) {
      int c = i * 256 + t;
      int r = c >> 3, cc = (c & 7) * 8;
      *(uint4*)&tile[r][cc] = *(const uint4*)(src + (size_t)r * NN + cc);
    }
  } else {
    const float* src = cacheV + ((size_t)h * LL + l0) * DD + d0;
#pragma unroll
    for (int i = 0; i < 4; ++i) {
      int c = i * 256 + t;
      int r = c >> 4, cc = (c & 15) * 4;
      float4 v = *(const float4*)(src + (size_t)r * DD + cc);
      tile[r][cc + 0] = f2bf(v.x);
      tile[r][cc + 1] = f2bf(v.y);
      tile[r][cc + 2] = f2bf(v.z);
      tile[r][cc + 3] = f2bf(v.w);
    }
  }
  __syncthreads();
#pragma unroll
  for (int i = 0; i < 2; ++i) {
    int c = i * 256 + t;
    int j = c >> 3, kk = (c & 7) * 8;
    union { ushort s[8]; uint4 v; } pk;
#pragma unroll
    for (int u = 0; u < 8; ++u) pk.s[u] = tile[kk + u][j];
    *(uint4*)(Vt + ((size_t)(h * DD + d0 + j)) * LL + l0 + kk) = pk.v;
  }
}

// ---------------- QKV GEMM: C[m][col] = sum_k Xb[m][k] * Wt[col][k] ----------------
// 128x128 tile, BK=64, global_load_lds(16B), XOR-swizzled LDS chunks.
__global__ __launch_bounds__(256) void qkv_gemm_kernel(
    const ushort* __restrict__ X, const ushort* __restrict__ Wt,
    ushort* __restrict__ q_ws, ushort* __restrict__ k_ws,
    ushort* __restrict__ v_ws) {
  __shared__ __align__(16) ushort Alds[128 * 64];
  __shared__ __align__(16) ushort Blds[128 * 64];
  int t = threadIdx.x;
  int lane = t & 63, quad = lane >> 4, l15 = lane & 15;
  int wv = t >> 6, wm = wv >> 1, wn = wv & 1;
  int m0 = blockIdx.x * 128;
  int wsel = blockIdx.y >> 5;
  int col0 = (blockIdx.y & 31) * 128;
  const ushort* Wsrc = Wt + (size_t)wsel * NN * NN + (size_t)col0 * NN;
  ushort* dst = (wsel == 0) ? q_ws : ((wsel == 1) ? k_ws : v_ws);

  int wuni = __builtin_amdgcn_readfirstlane(t & 192);  // wave base thread

  const ushort* aG[4];
  const ushort* bG[4];
  unsigned ldsb[4];
#pragma unroll
  for (int i = 0; i < 4; ++i) {
    int c = i * 256 + t;
    int row = c >> 3, g = (c & 7) ^ (row & 7);
    aG[i] = X + (size_t)(m0 + row) * NN + g * 8;
    bG[i] = Wsrc + (size_t)row * NN + g * 8;
    ldsb[i] = (unsigned)(i * 256 + wuni) * 16u;
  }
  unsigned aAddr[4][2], bAddr[4][2];
#pragma unroll
  for (int mb = 0; mb < 4; ++mb)
#pragma unroll
    for (int s = 0; s < 2; ++s) {
      int row = wm * 64 + mb * 16 + l15;
      int g = s * 4 + quad;
      aAddr[mb][s] = (unsigned)(row * 128 + ((g ^ (row & 7)) * 16));
    }
#pragma unroll
  for (int nb = 0; nb < 4; ++nb)
#pragma unroll
    for (int s = 0; s < 2; ++s) {
      int row = wn * 64 + nb * 16 + l15;
      int g = s * 4 + quad;
      bAddr[nb][s] = (unsigned)(row * 128 + ((g ^ (row & 7)) * 16));
    }

  f32x4 acc[4][4];
#pragma unroll
  for (int mb = 0; mb < 4; ++mb)
#pragma unroll
    for (int nb = 0; nb < 4; ++nb) acc[mb][nb] = (f32x4){0.f, 0.f, 0.f, 0.f};

  for (int kt = 0; kt < 64; ++kt) {
#pragma unroll
    for (int i = 0; i < 4; ++i) gl_lds16(aG[i], (char*)Alds + ldsb[i]);
#pragma unroll
    for (int i = 0; i < 4; ++i) gl_lds16(bG[i], (char*)Blds + ldsb[i]);
#pragma unroll
    for (int i = 0; i < 4; ++i) { aG[i] += 64; bG[i] += 64; }
    __syncthreads();  // drains vmcnt -> tiles visible
#pragma unroll
    for (int s = 0; s < 2; ++s) {
      short8 af[4], bf[4];
#pragma unroll
      for (int mb = 0; mb < 4; ++mb)
        af[mb] = *(const short8*)((const char*)Alds + aAddr[mb][s]);
#pragma unroll
      for (int nb = 0; nb < 4; ++nb)
        bf[nb] = *(const short8*)((const char*)Blds + bAddr[nb][s]);
#pragma unroll
      for (int mb = 0; mb < 4; ++mb)
#pragma unroll
        for (int nb = 0; nb < 4; ++nb)
          acc[mb][nb] = __builtin_amdgcn_mfma_f32_16x16x32_bf16(
              af[mb], bf[nb], acc[mb][nb], 0, 0, 0);
    }
    __syncthreads();  // done reading before next stage overwrites
  }

#pragma unroll
  for (int mb = 0; mb < 4; ++mb)
#pragma unroll
    for (int nb = 0; nb < 4; ++nb)
#pragma unroll
      for (int r = 0; r < 4; ++r) {
        int row = m0 + wm * 64 + mb * 16 + quad * 4 + r;
        int col = col0 + wn * 64 + nb * 16 + l15;
        dst[(size_t)row * NN + col] = f2bf(acc[mb][nb][r]);
      }
}

// ---------------- fused attention: one head x 64 queries per block ----------------
// Pipelined: K double-buffered in LDS with 1-tile-ahead global_load_lds prefetch
// and counted vmcnt (never 0 in steady state); V staged at top of iteration and
// waited only at vmcnt(4) after QK^T (latency hidden under MFMA+exp).
__global__ __launch_bounds__(256) void attn_kernel(
    const ushort* __restrict__ q_ws, const ushort* __restrict__ k_ws,
    const ushort* __restrict__ Kb, const ushort* __restrict__ Vt,
    float* __restrict__ out) {
  // LDS layout:
  //   Klds[2]: [64l][128d] bf16, xor16 chunk swizzle @0 / @16384  (32 KiB)
  //   Vlds:    [128d][64l] bf16, xor8                @32768       (16 KiB)
  //   Plds:    [64m][72l]  bf16, pitch 144B          @49152       (9216 B)
  //   den:     float[64]                             @58368       (256 B)
  //   Olds:    float[64][136] (epilogue reuse)       @0           (34816 B)
  // 58.6 KB -> 2 blocks/CU; grid 512 = 2/CU fully co-resident.
  __shared__ __align__(16) char smem[58624];
  float* denlds = (float*)(smem + 58368);
  float* Olds = (float*)smem;

  int t = threadIdx.x;
  int lane = t & 63, quad = lane >> 4, l15 = lane & 15;
  int wv = t >> 6;
  // XCD-aware bijective swizzle (512 blocks % 8 XCDs == 0):
  // each XCD gets a contiguous chunk of 64 blocks = 4 heads -> K/V L2-resident.
  int flat = (int)(blockIdx.y * 16 + blockIdx.x);
  int swz = ((flat & 7) << 6) | (flat >> 3);
  int m0 = (swz & 15) * 64;
  int h = swz >> 4;
  int wuni = __builtin_amdgcn_readfirstlane(t & 192);

  // Q fragments (A-layout): rows m0 + wv*16 + l15
  short8 qf[4];
  {
    const ushort* qrow =
        q_ws + (size_t)(m0 + wv * 16 + l15) * NN + h * DD + quad * 8;
#pragma unroll
    for (int s = 0; s < 4; ++s) qf[s] = *(const short8*)(qrow + s * 32);
  }

  // staging maps
  int kRow[4], kOff[4];
  unsigned kLb[4];
  const ushort* vG[4];
  unsigned vLb[4];
#pragma unroll
  for (int i = 0; i < 4; ++i) {
    int c = i * 256 + t;
    int krow = c >> 4, kg = (c & 15) ^ (krow & 15);
    kRow[i] = krow; kOff[i] = kg * 8;
    kLb[i] = (unsigned)(i * 256 + wuni) * 16u;
    int vrow = c >> 3, vg = (c & 7) ^ (vrow & 7);
    vG[i] = Vt + ((size_t)(h * DD + vrow)) * LL + vg * 8;
    vLb[i] = 32768u + (unsigned)(i * 256 + wuni) * 16u;
  }
  // fragment LDS addresses (iteration-invariant)
  unsigned kAddr[4][4], vAddr[2][2], pAddr[2][4];
#pragma unroll
  for (int lb = 0; lb < 4; ++lb)
#pragma unroll
    for (int ds = 0; ds < 4; ++ds) {
      int l = lb * 16 + l15, g = ds * 4 + quad;
      kAddr[lb][ds] = (unsigned)(l * 256 + ((g ^ l15) * 16));
    }
#pragma unroll
  for (int ls = 0; ls < 2; ++ls)
#pragma unroll
    for (int db = 0; db < 2; ++db) {
      int d = wv * 32 + db * 16 + l15, g = ls * 4 + quad;
      vAddr[ls][db] = 32768u + (unsigned)(d * 128 + ((g ^ (l15 & 7)) * 16));
    }
#pragma unroll
  for (int ls = 0; ls < 2; ++ls)
#pragma unroll
    for (int mb = 0; mb < 4; ++mb)
      pAddr[ls][mb] =
          49152u + (unsigned)((mb * 16 + l15) * 144 + ls * 64 + quad * 16);

  f32x4 Oacc[2][4];
#pragma unroll
  for (int db = 0; db < 2; ++db)
#pragma unroll
    for (int mb = 0; mb < 4; ++mb) Oacc[db][mb] = (f32x4){0.f, 0.f, 0.f, 0.f};
  float denp[4] = {0.f, 0.f, 0.f, 0.f};

  // prologue: stage K tile 0 into Klds buf 0 (l0 = 0 -> cache region)
  {
    const ushort* ks = Kb + (size_t)h * LL * DD;
#pragma unroll
    for (int i = 0; i < 4; ++i)
      gl_lds16(ks + (size_t)kRow[i] * DD + kOff[i], smem + kLb[i]);
  }

  for (int lt = 0; lt < 64; ++lt) {
    unsigned krd = (unsigned)(lt & 1) << 14;  // read buffer base
    // (1) issue K prefetch for tile lt+1 into the other buffer
    if (lt < 63) {
      int l0n = (lt + 1) * 64;
      const ushort* ks2;
      size_t kst2;
      if (l0n >= PP && l0n < PP + MM) {
        ks2 = k_ws + (size_t)(l0n - PP) * NN + h * DD;
        kst2 = NN;
      } else {
        ks2 = Kb + ((size_t)h * LL + l0n) * DD;
        kst2 = DD;
      }
      unsigned kb = krd ^ 16384u;
#pragma unroll
      for (int i = 0; i < 4; ++i)
        gl_lds16(ks2 + (size_t)kRow[i] * kst2 + kOff[i], smem + kb + kLb[i]);
    }
    // (2) issue V stage for tile lt (single buffer, consumed after barrier 2)
#pragma unroll
    for (int i = 0; i < 4; ++i) {
      gl_lds16(vG[i], smem + vLb[i]);
      vG[i] += 64;
    }
    // (3) wait K(lt) ready; leave K(lt+1)+V(lt) = 8 loads in flight
    if (lt < 63)
      asm volatile("s_waitcnt vmcnt(8)" ::: "memory");
    else
      asm volatile("s_waitcnt vmcnt(4)" ::: "memory");
    __builtin_amdgcn_s_barrier();
    asm volatile("" ::: "memory");

    // (4) S = Q K^T, exp, write P to LDS, accumulate denominator
    __builtin_amdgcn_s_setprio(1);
#pragma unroll
    for (int lb = 0; lb < 4; ++lb) {
      f32x4 s = (f32x4){0.f, 0.f, 0.f, 0.f};
#pragma unroll
      for (int ds = 0; ds < 4; ++ds) {
        short8 bk = *(const short8*)(smem + krd + kAddr[lb][ds]);
        s = __builtin_amdgcn_mfma_f32_16x16x32_bf16(qf[ds], bk, s, 0, 0, 0);
      }
#pragma unroll
      for (int r = 0; r < 4; ++r) {
        float e = __expf(s[r]);
        denp[r] += e;
        *(ushort*)(smem + 49152 + (wv * 16 + quad * 4 + r) * 144 +
                   (lb * 16 + l15) * 2) = f2bf(e);
      }
    }
    __builtin_amdgcn_s_setprio(0);

    // (5) V(lt) landed + P written; leave only K(lt+1) in flight
    if (lt < 63)
      asm volatile("s_waitcnt vmcnt(4) lgkmcnt(0)" ::: "memory");
    else
      asm volatile("s_waitcnt vmcnt(0) lgkmcnt(0)" ::: "memory");
    __builtin_amdgcn_s_barrier();
    asm volatile("" ::: "memory");

    // (6) O^T += V^T P^T  (wave wv owns d rows [wv*32, wv*32+32))
    __builtin_amdgcn_s_setprio(1);
#pragma unroll
    for (int ls = 0; ls < 2; ++ls) {
      short8 av0 = *(const short8*)(smem + vAddr[ls][0]);
      short8 av1 = *(const short8*)(smem + vAddr[ls][1]);
#pragma unroll
      for (int mb = 0; mb < 4; ++mb) {
        short8 bp = *(const short8*)(smem + pAddr[ls][mb]);
        Oacc[0][mb] =
            __builtin_amdgcn_mfma_f32_16x16x32_bf16(av0, bp, Oacc[0][mb], 0, 0, 0);
        Oacc[1][mb] =
            __builtin_amdgcn_mfma_f32_16x16x32_bf16(av1, bp, Oacc[1][mb], 0, 0, 0);
      }
    }
    __builtin_amdgcn_s_setprio(0);

    // (7) all reads of Vlds/Plds done before next iteration's writes
    asm volatile("" ::: "memory");
    __builtin_amdgcn_s_barrier();
    asm volatile("" ::: "memory");
  }

  __syncthreads();  // final PV done; smem reusable
  // denominator reduction across the 16 cols (lane bits 0..3)
#pragma unroll
  for (int r = 0; r < 4; ++r) {
    float v = denp[r];
    v += __shfl_xor(v, 1);
    v += __shfl_xor(v, 2);
    v += __shfl_xor(v, 4);
    v += __shfl_xor(v, 8);
    denp[r] = v;
  }
  if (l15 == 0) {
#pragma unroll
    for (int r = 0; r < 4; ++r) denlds[wv * 16 + quad * 4 + r] = denp[r];
  }
  __syncthreads();

  // divide + transpose O^T -> O via LDS (fp32, pitch 136)
#pragma unroll
  for (int mb = 0; mb < 4; ++mb) {
    float inv = 1.0f / denlds[mb * 16 + l15];
#pragma unroll
    for (int db = 0; db < 2; ++db)
#pragma unroll
      for (int r = 0; r < 4; ++r) {
        int d = wv * 32 + db * 16 + quad * 4 + r;
        Olds[(mb * 16 + l15) * 136 + d] = Oacc[db][mb][r] * inv;
      }
  }
  __syncthreads();
  {
    int m = t >> 2, c0 = (t & 3) * 32;
    float* orow = out + (size_t)(m0 + m) * NN + h * DD + c0;
#pragma unroll
    for (int j = 0; j < 32; j += 4) {
      float4 v;
      v.x = Olds[m * 136 + c0 + j + 0];
      v.y = Olds[m * 136 + c0 + j + 1];
      v.z = Olds[m * 136 + c0 + j + 2];
      v.w = Olds[m * 136 + c0 + j + 3];
      *(float4*)(orow + j) = v;
    }
  }
}

extern "C" void kernel_launch(void* const* d_in, const int* in_sizes, int n_in,
                              void* d_out, int out_size, void* d_ws,
                              size_t ws_size, hipStream_t stream) {
  const float* X = (const float*)d_in[0];
  const float* Wq = (const float*)d_in[1];
  const float* Wk = (const float*)d_in[2];
  const float* Wv = (const float*)d_in[3];
  const float* cK = (const float*)d_in[4];
  const float* cV = (const float*)d_in[5];
  float* out = (float*)d_out;
  char* wsb = (char*)d_ws;

  // ws layout (bytes) — Kb/Vt alias Wt (dead after GEMM). Total 128 MiB.
  ushort* Wt = (ushort*)wsb;                         // 100,663,296
  ushort* Kb = (ushort*)wsb;                         // 33,554,432 (alias)
  ushort* Vt = (ushort*)(wsb + 33554432);            // 33,554,432 (alias)
  ushort* Xb = (ushort*)(wsb + 100663296);           // 8,388,608
  ushort* q_ws = (ushort*)(wsb + 109051904);         // 8,388,608
  ushort* k_ws = (ushort*)(wsb + 117440512);         // 8,388,608
  ushort* v_ws = (ushort*)(wsb + 125829120);         // 8,388,608

  convert_kernel<<<2048, 256, 0, stream>>>(X, Xb, MM * NN / 8);
  transpose_w_kernel<<<dim3(64, 64, 3), 256, 0, stream>>>(Wq, Wk, Wv, Wt);
  qkv_gemm_kernel<<<dim3(8, 96), 256, 0, stream>>>(Xb, Wt, q_ws, k_ws, v_ws);
  convert_kernel<<<8192, 256, 0, stream>>>(cK, Kb, HH * LL * DD / 8);
  transpose_v_kernel<<<dim3(64, 2, 32), 256, 0, stream>>>(cV, v_ws, Vt);
  attn_kernel<<<dim3(16, 32), 256, 0, stream>>>(q_ws, k_ws, Kb, Vt, out);
}